// Round 2
// baseline (490.238 us; speedup 1.0000x reference)
//
#include <hip/hip_runtime.h>
#include <hip/hip_bf16.h>
#include <math.h>

#define HID 128
#define BSEQ 8192
#define BSH 4096
#define RELS 1000

// Workspace layout (bytes):
//  [0,64)              double acc[8]: 0=h2 1=r2 2=t2 3=wrsq 4=margin
//  [64, 64+4000)       int winner[1000]
//  [4096, 53248)       float abc[3*4096]: a | b | c
//  [53248, +4194304)   float e[8192][128]

__global__ void k_init(double* __restrict__ acc, int* __restrict__ winner) {
    int t = blockIdx.x * blockDim.x + threadIdx.x;
    if (t < 8) acc[t] = 0.0;
    if (t < RELS) winner[t] = -1;
}

// 2 rows per block (256 threads, 128 per row): e = |h + r - t|, accumulate norms
__global__ __launch_bounds__(256) void k_gather(const int* __restrict__ idx,
                                                const float* __restrict__ ent,
                                                const float* __restrict__ rel,
                                                float* __restrict__ e,
                                                double* __restrict__ acc) {
    int row = blockIdx.x * 2 + (threadIdx.x >> 7);
    int k = threadIdx.x & 127;
    int i0 = idx[row * 3 + 0];
    int i1 = idx[row * 3 + 1];
    int i2 = idx[row * 3 + 2];
    float h = ent[(size_t)i0 * HID + k];
    float r = rel[(size_t)i1 * HID + k];
    float t = ent[(size_t)i2 * HID + k];
    e[(size_t)row * HID + k] = fabsf(h + r - t);
    float hh = h * h, rr = r * r, tt = t * t;
    #pragma unroll
    for (int off = 32; off; off >>= 1) {
        hh += __shfl_down(hh, off);
        rr += __shfl_down(rr, off);
        tt += __shfl_down(tt, off);
    }
    __shared__ float sh[3][4];
    int lane = threadIdx.x & 63, wv = threadIdx.x >> 6;
    if (lane == 0) { sh[0][wv] = hh; sh[1][wv] = rr; sh[2][wv] = tt; }
    __syncthreads();
    if (threadIdx.x == 0) {
        atomicAdd(&acc[0], (double)(sh[0][0] + sh[0][1] + sh[0][2] + sh[0][3]));
        atomicAdd(&acc[1], (double)(sh[1][0] + sh[1][1] + sh[1][2] + sh[1][3]));
        atomicAdd(&acc[2], (double)(sh[2][0] + sh[2][1] + sh[2][2] + sh[2][3]));
    }
}

// one wave per row j: a=ep.en b=ep.ep c=en.en, wr_sumsq term, winner scatter-arg
__global__ __launch_bounds__(256) void k_rowstats(const int* __restrict__ idx,
                                                  const float* __restrict__ e,
                                                  float* __restrict__ abc,
                                                  int* __restrict__ winner,
                                                  double* __restrict__ acc) {
    int wv = threadIdx.x >> 6, lane = threadIdx.x & 63;
    int j = blockIdx.x * 4 + wv;  // grid = 1024
    const float* ep = e + (size_t)j * HID;
    const float* en = e + (size_t)(j + BSH) * HID;
    float ep0 = ep[lane], ep1 = ep[lane + 64];
    float en0 = en[lane], en1 = en[lane + 64];
    float a = ep0 * en0 + ep1 * en1;
    float b = ep0 * ep0 + ep1 * ep1;
    float c = en0 * en0 + en1 * en1;
    #pragma unroll
    for (int off = 32; off; off >>= 1) {
        a += __shfl_down(a, off);
        b += __shfl_down(b, off);
        c += __shfl_down(c, off);
    }
    if (lane == 0) {
        abc[j] = a; abc[BSH + j] = b; abc[2 * BSH + j] = c;
        double ad = a, bd = b, cd = c;
        atomicAdd(&acc[3], cd * cd - 2.0 * ad * ad + bd * bd);
        atomicMax(&winner[idx[j * 3 + 1]], j);  // last-write-wins (max j)
    }
}

// one block per relation: write Wr_new row (computed for winners, copied else)
__global__ __launch_bounds__(256) void k_wrout(const float* __restrict__ Wr,
                                               const float* __restrict__ e,
                                               const int* __restrict__ winner,
                                               float* __restrict__ outWr) {
    int rel = blockIdx.x;
    int t = threadIdx.x;
    float* out = outWr + (size_t)rel * HID * HID;
    int j = winner[rel];
    if (j < 0) {
        const float* src = Wr + (size_t)rel * HID * HID;
        #pragma unroll 8
        for (int it = 0; it < 64; ++it) out[it * 256 + t] = src[it * 256 + t];
    } else {
        __shared__ float sep[HID], sen[HID];
        if (t < 128) sep[t] = e[(size_t)j * HID + t];
        else sen[t - 128] = e[(size_t)(j + BSH) * HID + (t - 128)];
        __syncthreads();
        #pragma unroll 8
        for (int it = 0; it < 64; ++it) {
            int ix = it * 256 + t;
            int hh = ix >> 7, kk = ix & 127;
            out[ix] = sen[hh] * sen[kk] - sep[hh] * sep[kk];
        }
    }
}

// 64x64 tile per block over the (bi<=bj) triangle.
// 3-product identity: with u = ep+en,
//   ep_i.en_j + en_i.ep_j = u_i.u_j - ep_i.ep_j - en_i.en_j
// so score(i,j) = a_j*q - (a_j+b_j)*p2 - (a_j+c_j)*p3 + 1,
//   q = u_i.u_j, p2 = ep_i.ep_j, p3 = en_i.en_j  (all i<->j symmetric).
__global__ __launch_bounds__(256) void k_score(const float* __restrict__ e,
                                               const float* __restrict__ abc,
                                               double* __restrict__ acc) {
    int bi = blockIdx.y, bj = blockIdx.x;
    if (bj < bi) return;
    const int I0 = bi * 64, J0 = bj * 64;
    // k-major LDS: [k within chunk][row], padded to 68 (16B-aligned rows of k)
    __shared__ float sEpI[32][68], sEnI[32][68], sEpJ[32][68], sEnJ[32][68];
    __shared__ float sRed[4];
    const int t = threadIdx.x;
    const int tx = t & 15, ty = t >> 4;

    float q[4][4] = {}, p2[4][4] = {}, p3[4][4] = {};

    const int srow = t >> 3;          // 0..31
    const int c0 = (t & 7) * 4;       // 0..28 step 4

    for (int kc = 0; kc < 4; ++kc) {
        __syncthreads();
        const int kbase = kc * 32 + c0;
        #pragma unroll
        for (int half = 0; half < 2; ++half) {
            int rr = srow + half * 32;
            float4 vEpI = *(const float4*)&e[(size_t)(I0 + rr) * HID + kbase];
            float4 vEnI = *(const float4*)&e[(size_t)(BSH + I0 + rr) * HID + kbase];
            float4 vEpJ = *(const float4*)&e[(size_t)(J0 + rr) * HID + kbase];
            float4 vEnJ = *(const float4*)&e[(size_t)(BSH + J0 + rr) * HID + kbase];
            sEpI[c0 + 0][rr] = vEpI.x; sEpI[c0 + 1][rr] = vEpI.y;
            sEpI[c0 + 2][rr] = vEpI.z; sEpI[c0 + 3][rr] = vEpI.w;
            sEnI[c0 + 0][rr] = vEnI.x; sEnI[c0 + 1][rr] = vEnI.y;
            sEnI[c0 + 2][rr] = vEnI.z; sEnI[c0 + 3][rr] = vEnI.w;
            sEpJ[c0 + 0][rr] = vEpJ.x; sEpJ[c0 + 1][rr] = vEpJ.y;
            sEpJ[c0 + 2][rr] = vEpJ.z; sEpJ[c0 + 3][rr] = vEpJ.w;
            sEnJ[c0 + 0][rr] = vEnJ.x; sEnJ[c0 + 1][rr] = vEnJ.y;
            sEnJ[c0 + 2][rr] = vEnJ.z; sEnJ[c0 + 3][rr] = vEnJ.w;
        }
        __syncthreads();
        #pragma unroll 4
        for (int k = 0; k < 32; ++k) {
            float4 aEp = *(const float4*)&sEpI[k][ty * 4];
            float4 aEn = *(const float4*)&sEnI[k][ty * 4];
            float4 bEp = *(const float4*)&sEpJ[k][tx * 4];
            float4 bEn = *(const float4*)&sEnJ[k][tx * 4];
            float epI[4] = {aEp.x, aEp.y, aEp.z, aEp.w};
            float enI[4] = {aEn.x, aEn.y, aEn.z, aEn.w};
            float epJ[4] = {bEp.x, bEp.y, bEp.z, bEp.w};
            float enJ[4] = {bEn.x, bEn.y, bEn.z, bEn.w};
            float uI[4], uJ[4];
            #pragma unroll
            for (int ii = 0; ii < 4; ++ii) uI[ii] = epI[ii] + enI[ii];
            #pragma unroll
            for (int jj = 0; jj < 4; ++jj) uJ[jj] = epJ[jj] + enJ[jj];
            #pragma unroll
            for (int ii = 0; ii < 4; ++ii)
                #pragma unroll
                for (int jj = 0; jj < 4; ++jj) {
                    q[ii][jj]  = fmaf(uI[ii],  uJ[jj],  q[ii][jj]);
                    p2[ii][jj] = fmaf(epI[ii], epJ[jj], p2[ii][jj]);
                    p3[ii][jj] = fmaf(enI[ii], enJ[jj], p3[ii][jj]);
                }
        }
    }

    // epilogue: score(i,j) always; score(j,i) for off-diagonal tiles
    const float* A = abc;
    const float* Bv = abc + BSH;
    const float* Cv = abc + 2 * BSH;
    float lsum = 0.f;
    #pragma unroll
    for (int jj = 0; jj < 4; ++jj) {
        int j = J0 + tx * 4 + jj;
        float aj = A[j], abj = aj + Bv[j], acj = aj + Cv[j];
        #pragma unroll
        for (int ii = 0; ii < 4; ++ii) {
            float s = fmaf(aj, q[ii][jj], 1.0f) - abj * p2[ii][jj] - acj * p3[ii][jj];
            lsum += fmaxf(s, 0.f);
        }
    }
    if (bj != bi) {
        #pragma unroll
        for (int ii = 0; ii < 4; ++ii) {
            int i = I0 + ty * 4 + ii;
            float ai = A[i], abi = ai + Bv[i], aci = ai + Cv[i];
            #pragma unroll
            for (int jj = 0; jj < 4; ++jj) {
                float s = fmaf(ai, q[ii][jj], 1.0f) - abi * p2[ii][jj] - aci * p3[ii][jj];
                lsum += fmaxf(s, 0.f);
            }
        }
    }
    #pragma unroll
    for (int off = 32; off; off >>= 1) lsum += __shfl_down(lsum, off);
    int lane = t & 63, wv = t >> 6;
    if (lane == 0) sRed[wv] = lsum;
    __syncthreads();
    if (t == 0)
        atomicAdd(&acc[4], (double)(sRed[0] + sRed[1] + sRed[2] + sRed[3]));
}

__global__ void k_final(const double* __restrict__ acc, float* __restrict__ out) {
    double margin = acc[4] / (double)BSH;
    double wr = sqrt(acc[3]) * 0.01;
    double nl = (sqrt(acc[0]) + sqrt(acc[1]) + sqrt(acc[2])) * 0.01;
    out[0] = (float)(margin + wr + nl);
}

extern "C" void kernel_launch(void* const* d_in, const int* in_sizes, int n_in,
                              void* d_out, int out_size, void* d_ws, size_t ws_size,
                              hipStream_t stream) {
    const int* idx = (const int*)d_in[0];
    const float* ent = (const float*)d_in[1];
    const float* rel = (const float*)d_in[2];
    const float* Wr = (const float*)d_in[3];
    float* out = (float*)d_out;

    char* ws = (char*)d_ws;
    double* acc = (double*)ws;
    int* winner = (int*)(ws + 64);
    float* abc = (float*)(ws + 4096);
    float* e = (float*)(ws + 53248);

    k_init<<<4, 256, 0, stream>>>(acc, winner);
    k_gather<<<BSEQ / 2, 256, 0, stream>>>(idx, ent, rel, e, acc);
    k_rowstats<<<BSH / 4, 256, 0, stream>>>(idx, e, abc, winner, acc);
    k_wrout<<<RELS, 256, 0, stream>>>(Wr, e, winner, out + 1);
    k_score<<<dim3(64, 64), 256, 0, stream>>>(e, abc, acc);
    k_final<<<1, 1, 0, stream>>>(acc, out);
}

// Round 4
// 409.326 us; speedup vs baseline: 1.1977x; 1.1977x over previous
//
#include <hip/hip_runtime.h>
#include <hip/hip_bf16.h>
#include <math.h>

#define HID 128
#define BSEQ 8192
#define BSH 4096
#define RELS 1000
#define KEXT 256   // 128 elems x (hi,lo) bf16 interleaved

typedef unsigned int u32;
typedef __attribute__((ext_vector_type(8))) short bf16x8;
typedef __attribute__((ext_vector_type(4))) float f32x4;

// d_ws layout (bytes)  [proven available: 4.25 MB]:
//  [0,64)                double acc[8]: 0=h2 1=r2 2=t2 3=wrsq 4=margin
//  [64, 64+4000)         int winner[1000]
//  [4096, 53248)         float abc[3*4096]: a | b | c
//  [53248, 4247552)      float e[8192][128]
// d_out scratch (written before k_wrout overwrites it):
//  S = (ushort*)(d_out + 4): ushort S[3][4096][256]   (u | ep | en, [hi,lo] pairs)

__device__ inline unsigned short f2bf(float x) {  // RNE bf16
    u32 u = __float_as_uint(x);
    u32 r = (u + 0x7fff + ((u >> 16) & 1)) >> 16;
    return (unsigned short)r;
}

__device__ inline u32 pack2bf(float x) {  // [hi, lo] packed u32
    unsigned short hi = f2bf(x);
    float hf = __uint_as_float((u32)hi << 16);
    unsigned short lo = f2bf(x - hf);
    return (u32)hi | ((u32)lo << 16);
}

#define GLOAD_LDS16(g, l) __builtin_amdgcn_global_load_lds( \
    (const __attribute__((address_space(1))) u32*)(g), \
    (__attribute__((address_space(3))) u32*)(l), 16, 0, 0)

__global__ void k_init(double* __restrict__ acc, int* __restrict__ winner) {
    int t = blockIdx.x * blockDim.x + threadIdx.x;
    if (t < 8) acc[t] = 0.0;
    if (t < RELS) winner[t] = -1;
}

// Fused gather + norms + bf16-split + rowstats. Block b owns rows b (ep) and
// b+BSH (en): threads 0..127 = ep elems, 128..255 = en elems.
__global__ __launch_bounds__(256) void k_prep(const int* __restrict__ idx,
                                              const float* __restrict__ ent,
                                              const float* __restrict__ rel,
                                              float* __restrict__ e,
                                              u32* __restrict__ S,
                                              float* __restrict__ abc,
                                              int* __restrict__ winner,
                                              double* __restrict__ acc) {
    const int b = blockIdx.x;
    const int half = threadIdx.x >> 7;   // 0=ep row b, 1=en row b+BSH
    const int k = threadIdx.x & 127;
    const int row = half ? (b + BSH) : b;
    const int i0 = idx[row * 3 + 0];
    const int i1 = idx[row * 3 + 1];
    const int i2 = idx[row * 3 + 2];
    const float h = ent[(size_t)i0 * HID + k];
    const float r = rel[(size_t)i1 * HID + k];
    const float t = ent[(size_t)i2 * HID + k];
    const float val = fabsf(h + r - t);
    e[(size_t)row * HID + k] = val;

    __shared__ float sE[2][128];
    __shared__ float sh[3][4];
    __shared__ float sPart[3][2];
    sE[half][k] = val;

    // norm partial sums (per wave)
    float hh = h * h, rr = r * r, tt = t * t;
    #pragma unroll
    for (int off = 32; off; off >>= 1) {
        hh += __shfl_down(hh, off);
        rr += __shfl_down(rr, off);
        tt += __shfl_down(tt, off);
    }
    int lane = threadIdx.x & 63, wv = threadIdx.x >> 6;
    if (lane == 0) { sh[0][wv] = hh; sh[1][wv] = rr; sh[2][wv] = tt; }
    __syncthreads();

    if (threadIdx.x == 0) {
        atomicAdd(&acc[0], (double)(sh[0][0] + sh[0][1] + sh[0][2] + sh[0][3]));
        atomicAdd(&acc[1], (double)(sh[1][0] + sh[1][1] + sh[1][2] + sh[1][3]));
        atomicAdd(&acc[2], (double)(sh[2][0] + sh[2][1] + sh[2][2] + sh[2][3]));
    }

    const float p = sE[0][k], n = sE[1][k];
    // bf16 splits: S row = 128 packed u32 ([hi,lo] per element; K-permutation ok)
    {
        size_t base = ((size_t)(1 + half) * BSH + b) * (KEXT / 2);
        S[base + k] = pack2bf(val);
        if (half == 0) {
            size_t ub = (size_t)b * (KEXT / 2);
            S[ub + k] = pack2bf(p + n);
        }
    }
    // rowstats on threads 0..127 (waves 0,1)
    if (half == 0) {
        float ak = p * n, bk = p * p, ck = n * n;
        #pragma unroll
        for (int off = 32; off; off >>= 1) {
            ak += __shfl_down(ak, off);
            bk += __shfl_down(bk, off);
            ck += __shfl_down(ck, off);
        }
        if (lane == 0) { sPart[0][wv] = ak; sPart[1][wv] = bk; sPart[2][wv] = ck; }
    }
    __syncthreads();
    if (threadIdx.x == 0) {
        float a = sPart[0][0] + sPart[0][1];
        float bb = sPart[1][0] + sPart[1][1];
        float c = sPart[2][0] + sPart[2][1];
        abc[b] = a; abc[BSH + b] = bb; abc[2 * BSH + b] = c;
        double ad = a, bd = bb, cd = c;
        atomicAdd(&acc[3], cd * cd - 2.0 * ad * ad + bd * bd);
        atomicMax(&winner[i1], b);  // i1 of thread 0 = idx[b*3+1]; last-write-wins
    }
}

// MFMA Gram kernel: 64x64 tile per block over (bi<=bj) triangle.
// Three K=256 bf16 NT-GEMMs (q=u.u, p2=ep.ep, p3=en.en), m97-style
// 2-barrier loop, global_load_lds width-16 staging, BK=32.
// score(i,j) = a_j*q + 1 - (a_j+b_j)*p2 - (a_j+c_j)*p3
__global__ __launch_bounds__(256) void k_scoremm(const unsigned short* __restrict__ S,
                                                 const float* __restrict__ abc,
                                                 double* __restrict__ acc) {
    int bi = blockIdx.y, bj = blockIdx.x;
    if (bj < bi) return;
    const int I0 = bi * 64, J0 = bj * 64;
    // 6 arrays x 64 rows x 32 bf16 (64B pitch): [m*2+side][row][k]
    __shared__ __align__(16) unsigned short sAll[6 * 64 * 32];
    __shared__ float sRed[4];
    const int t = threadIdx.x;
    const int lane = t & 63, wv = t >> 6;
    const int wr = wv >> 1, wc = wv & 1;       // wave quadrant of 64x64
    const int lam = lane & 15, lag = lane >> 4;

    f32x4 a0[2][2] = {}, a1[2][2] = {}, a2[2][2] = {};  // q, p2, p3 accums

    for (int kc = 0; kc < 8; ++kc) {           // K = 8 x 32
        __syncthreads();
        #pragma unroll
        for (int qq = 0; qq < 6; ++qq) {
            int q = wv * 6 + qq;
            int b = q * 1024 + lane * 16;      // LDS byte offset == staging cursor
            int arr = b >> 12;                 // 0..5  (m*2+side)
            int within = b & 4095;
            int row = within >> 6;
            int colB = within & 63;
            int m = arr >> 1;
            int R0 = (arr & 1) ? J0 : I0;
            const unsigned short* src = S + ((size_t)(m * BSH + R0 + row) << 8)
                                          + kc * 32 + (colB >> 1);
            GLOAD_LDS16(src, &sAll[q * 512]);
        }
        __syncthreads();
        bf16x8 fa[3][2], fb[3][2];
        #pragma unroll
        for (int m = 0; m < 3; ++m) {
            #pragma unroll
            for (int f = 0; f < 2; ++f) {
                fa[m][f] = *(const bf16x8*)&sAll[(m * 2 + 0) * 2048
                              + (wr * 32 + f * 16 + lam) * 32 + lag * 8];
                fb[m][f] = *(const bf16x8*)&sAll[(m * 2 + 1) * 2048
                              + (wc * 32 + f * 16 + lam) * 32 + lag * 8];
            }
        }
        #pragma unroll
        for (int fi = 0; fi < 2; ++fi)
            #pragma unroll
            for (int fj = 0; fj < 2; ++fj) {
                a0[fi][fj] = __builtin_amdgcn_mfma_f32_16x16x32_bf16(fa[0][fi], fb[0][fj], a0[fi][fj], 0, 0, 0);
                a1[fi][fj] = __builtin_amdgcn_mfma_f32_16x16x32_bf16(fa[1][fi], fb[1][fj], a1[fi][fj], 0, 0, 0);
                a2[fi][fj] = __builtin_amdgcn_mfma_f32_16x16x32_bf16(fa[2][fi], fb[2][fj], a2[fi][fj], 0, 0, 0);
            }
    }

    // epilogue: C layout col=lane&15, row=(lane>>4)*4+reg (m89-verified)
    const float* A = abc;
    const float* Bv = abc + BSH;
    const float* Cv = abc + 2 * BSH;
    float lsum = 0.f;
    #pragma unroll
    for (int fj = 0; fj < 2; ++fj) {
        int j = J0 + wc * 32 + fj * 16 + lam;
        float aj = A[j], abj = aj + Bv[j], acj = aj + Cv[j];
        #pragma unroll
        for (int fi = 0; fi < 2; ++fi)
            #pragma unroll
            for (int r = 0; r < 4; ++r) {
                float s = fmaf(aj, a0[fi][fj][r], 1.0f)
                          - abj * a1[fi][fj][r] - acj * a2[fi][fj][r];
                lsum += fmaxf(s, 0.f);
            }
    }
    if (bj != bi) {
        #pragma unroll
        for (int fi = 0; fi < 2; ++fi)
            #pragma unroll
            for (int r = 0; r < 4; ++r) {
                int i = I0 + wr * 32 + fi * 16 + lag * 4 + r;
                float ai = A[i], abi = ai + Bv[i], aci = ai + Cv[i];
                #pragma unroll
                for (int fj = 0; fj < 2; ++fj) {
                    float s = fmaf(ai, a0[fi][fj][r], 1.0f)
                              - abi * a1[fi][fj][r] - aci * a2[fi][fj][r];
                    lsum += fmaxf(s, 0.f);
                }
            }
    }
    #pragma unroll
    for (int off = 32; off; off >>= 1) lsum += __shfl_down(lsum, off);
    if (lane == 0) sRed[wv] = lsum;
    __syncthreads();
    if (t == 0)
        atomicAdd(&acc[4], (double)(sRed[0] + sRed[1] + sRed[2] + sRed[3]));
}

// one block per relation: write Wr_new row (runs AFTER k_scoremm: d_out scratch dead)
__global__ __launch_bounds__(256) void k_wrout(const float* __restrict__ Wr,
                                               const float* __restrict__ e,
                                               const int* __restrict__ winner,
                                               float* __restrict__ outWr) {
    int rel = blockIdx.x;
    int t = threadIdx.x;
    float* out = outWr + (size_t)rel * HID * HID;
    int j = winner[rel];
    if (j < 0) {
        const float* src = Wr + (size_t)rel * HID * HID;
        #pragma unroll 8
        for (int it = 0; it < 64; ++it) out[it * 256 + t] = src[it * 256 + t];
    } else {
        __shared__ float sep[HID], sen[HID];
        if (t < 128) sep[t] = e[(size_t)j * HID + t];
        else sen[t - 128] = e[(size_t)(j + BSH) * HID + (t - 128)];
        __syncthreads();
        #pragma unroll 8
        for (int it = 0; it < 64; ++it) {
            int ix = it * 256 + t;
            int hh = ix >> 7, kk = ix & 127;
            out[ix] = sen[hh] * sen[kk] - sep[hh] * sep[kk];
        }
    }
}

__global__ void k_final(const double* __restrict__ acc, float* __restrict__ out) {
    double margin = acc[4] / (double)BSH;
    double wr = sqrt(acc[3]) * 0.01;
    double nl = (sqrt(acc[0]) + sqrt(acc[1]) + sqrt(acc[2])) * 0.01;
    out[0] = (float)(margin + wr + nl);
}

extern "C" void kernel_launch(void* const* d_in, const int* in_sizes, int n_in,
                              void* d_out, int out_size, void* d_ws, size_t ws_size,
                              hipStream_t stream) {
    const int* idx = (const int*)d_in[0];
    const float* ent = (const float*)d_in[1];
    const float* rel = (const float*)d_in[2];
    const float* Wr = (const float*)d_in[3];
    float* out = (float*)d_out;

    char* ws = (char*)d_ws;
    double* acc = (double*)ws;
    int* winner = (int*)(ws + 64);
    float* abc = (float*)(ws + 4096);
    float* e = (float*)(ws + 53248);
    // S lives in d_out (guaranteed 65.5 MB); consumed before k_wrout overwrites
    u32* S = (u32*)(out + 4);   // byte offset 16: 16B-aligned

    k_init<<<4, 256, 0, stream>>>(acc, winner);
    k_prep<<<BSH, 256, 0, stream>>>(idx, ent, rel, e, S, abc, winner, acc);
    k_scoremm<<<dim3(64, 64), 256, 0, stream>>>((const unsigned short*)S, abc, acc);
    k_wrout<<<RELS, 256, 0, stream>>>(Wr, e, winner, out + 1);
    k_final<<<1, 1, 0, stream>>>(acc, out);
}

// Round 5
// 222.576 us; speedup vs baseline: 2.2026x; 1.8390x over previous
//
#include <hip/hip_runtime.h>
#include <hip/hip_bf16.h>
#include <math.h>

#define HID 128
#define BSEQ 8192
#define BSH 4096
#define RELS 1000
#define KEXT 256   // 128 elems x (hi,lo) bf16 interleaved

typedef unsigned int u32;
typedef __attribute__((ext_vector_type(8))) short bf16x8;
typedef __attribute__((ext_vector_type(4))) float f32x4;

// d_ws layout (bytes)  [proven available: 4.25 MB]:
//  [64, 64+4000)         int winner[1000]
//  [4096, 53248)         float abc[3*4096]: a | b | c
//  [53248, 4247552)      float e[8192][128]
// d_out scratch (consumed by k_reduce BEFORE k_wrout overwrites):
//  byte 16:       ushort S[3][4096][256]   (u | ep | en, [hi,lo] pairs)  6.29 MB
//  byte 6291488:  double part_prep[4096][4]  (h2, r2, t2, wrsq)          128 KB
//  byte 6422560:  double part_margin[4096]                               32 KB

__device__ inline unsigned short f2bf(float x) {  // RNE bf16
    u32 u = __float_as_uint(x);
    u32 r = (u + 0x7fff + ((u >> 16) & 1)) >> 16;
    return (unsigned short)r;
}

__device__ inline u32 pack2bf(float x) {  // [hi, lo] packed u32
    unsigned short hi = f2bf(x);
    float hf = __uint_as_float((u32)hi << 16);
    unsigned short lo = f2bf(x - hf);
    return (u32)hi | ((u32)lo << 16);
}

#define GLOAD_LDS16(g, l) __builtin_amdgcn_global_load_lds( \
    (const __attribute__((address_space(1))) u32*)(g), \
    (__attribute__((address_space(3))) u32*)(l), 16, 0, 0)

__global__ void k_init(int* __restrict__ winner) {
    int t = blockIdx.x * blockDim.x + threadIdx.x;
    if (t < RELS) winner[t] = -1;
}

// Fused gather + norms + bf16-split + rowstats. Block b owns rows b (ep) and
// b+BSH (en). NO contended atomics: partials -> part_prep[b].
__global__ __launch_bounds__(256) void k_prep(const int* __restrict__ idx,
                                              const float* __restrict__ ent,
                                              const float* __restrict__ rel,
                                              float* __restrict__ e,
                                              u32* __restrict__ S,
                                              float* __restrict__ abc,
                                              int* __restrict__ winner,
                                              double* __restrict__ part) {
    const int b = blockIdx.x;
    const int half = threadIdx.x >> 7;   // 0=ep row b, 1=en row b+BSH
    const int k = threadIdx.x & 127;
    const int row = half ? (b + BSH) : b;
    const int i0 = idx[row * 3 + 0];
    const int i1 = idx[row * 3 + 1];
    const int i2 = idx[row * 3 + 2];
    const float h = ent[(size_t)i0 * HID + k];
    const float r = rel[(size_t)i1 * HID + k];
    const float t = ent[(size_t)i2 * HID + k];
    const float val = fabsf(h + r - t);
    e[(size_t)row * HID + k] = val;

    __shared__ float sE[2][128];
    __shared__ float sh[3][4];
    __shared__ float sPart[3][2];
    sE[half][k] = val;

    // norm partial sums (per wave)
    float hh = h * h, rr = r * r, tt = t * t;
    #pragma unroll
    for (int off = 32; off; off >>= 1) {
        hh += __shfl_down(hh, off);
        rr += __shfl_down(rr, off);
        tt += __shfl_down(tt, off);
    }
    int lane = threadIdx.x & 63, wv = threadIdx.x >> 6;
    if (lane == 0) { sh[0][wv] = hh; sh[1][wv] = rr; sh[2][wv] = tt; }
    __syncthreads();

    const float p = sE[0][k], n = sE[1][k];
    // bf16 splits: S row = 128 packed u32 ([hi,lo] per element; K-permutation ok)
    {
        size_t base = ((size_t)(1 + half) * BSH + b) * (KEXT / 2);
        S[base + k] = pack2bf(val);
        if (half == 0) {
            size_t ub = (size_t)b * (KEXT / 2);
            S[ub + k] = pack2bf(p + n);
        }
    }
    // rowstats on threads 0..127 (waves 0,1)
    if (half == 0) {
        float ak = p * n, bk = p * p, ck = n * n;
        #pragma unroll
        for (int off = 32; off; off >>= 1) {
            ak += __shfl_down(ak, off);
            bk += __shfl_down(bk, off);
            ck += __shfl_down(ck, off);
        }
        if (lane == 0) { sPart[0][wv] = ak; sPart[1][wv] = bk; sPart[2][wv] = ck; }
    }
    __syncthreads();
    if (threadIdx.x == 0) {
        float a = sPart[0][0] + sPart[0][1];
        float bb = sPart[1][0] + sPart[1][1];
        float c = sPart[2][0] + sPart[2][1];
        abc[b] = a; abc[BSH + b] = bb; abc[2 * BSH + b] = c;
        double ad = a, bd = bb, cd = c;
        part[(size_t)b * 4 + 0] = (double)(sh[0][0] + sh[0][1] + sh[0][2] + sh[0][3]);
        part[(size_t)b * 4 + 1] = (double)(sh[1][0] + sh[1][1] + sh[1][2] + sh[1][3]);
        part[(size_t)b * 4 + 2] = (double)(sh[2][0] + sh[2][1] + sh[2][2] + sh[2][3]);
        part[(size_t)b * 4 + 3] = cd * cd - 2.0 * ad * ad + bd * bd;
        atomicMax(&winner[i1], b);  // ~4 ops per address: uncontended
    }
}

// MFMA Gram kernel: 64x64 tile per block over (bi<=bj) triangle.
// Three K=256 bf16 NT-GEMMs (q=u.u, p2=ep.ep, p3=en.en).
// score(i,j) = a_j*q + 1 - (a_j+b_j)*p2 - (a_j+c_j)*p3
// Margin partial -> part_margin[flat block id]; inactive blocks write 0.
__global__ __launch_bounds__(256) void k_scoremm(const unsigned short* __restrict__ S,
                                                 const float* __restrict__ abc,
                                                 double* __restrict__ pm) {
    int bi = blockIdx.y, bj = blockIdx.x;
    const int flat = bi * 64 + bj;
    if (bj < bi) {
        if (threadIdx.x == 0) pm[flat] = 0.0;
        return;
    }
    const int I0 = bi * 64, J0 = bj * 64;
    // 6 arrays x 64 rows x 32 bf16 (64B pitch): [m*2+side][row][k]
    __shared__ __align__(16) unsigned short sAll[6 * 64 * 32];
    __shared__ float sRed[4];
    const int t = threadIdx.x;
    const int lane = t & 63, wv = t >> 6;
    const int wr = wv >> 1, wc = wv & 1;       // wave quadrant of 64x64
    const int lam = lane & 15, lag = lane >> 4;

    f32x4 a0[2][2] = {}, a1[2][2] = {}, a2[2][2] = {};  // q, p2, p3 accums

    for (int kc = 0; kc < 8; ++kc) {           // K = 8 x 32
        __syncthreads();
        #pragma unroll
        for (int qq = 0; qq < 6; ++qq) {
            int q = wv * 6 + qq;
            int b = q * 1024 + lane * 16;      // LDS byte offset == staging cursor
            int arr = b >> 12;                 // 0..5  (m*2+side)
            int within = b & 4095;
            int row = within >> 6;
            int colB = within & 63;
            int m = arr >> 1;
            int R0 = (arr & 1) ? J0 : I0;
            const unsigned short* src = S + ((size_t)(m * BSH + R0 + row) << 8)
                                          + kc * 32 + (colB >> 1);
            GLOAD_LDS16(src, &sAll[q * 512]);
        }
        __syncthreads();
        bf16x8 fa[3][2], fb[3][2];
        #pragma unroll
        for (int m = 0; m < 3; ++m) {
            #pragma unroll
            for (int f = 0; f < 2; ++f) {
                fa[m][f] = *(const bf16x8*)&sAll[(m * 2 + 0) * 2048
                              + (wr * 32 + f * 16 + lam) * 32 + lag * 8];
                fb[m][f] = *(const bf16x8*)&sAll[(m * 2 + 1) * 2048
                              + (wc * 32 + f * 16 + lam) * 32 + lag * 8];
            }
        }
        #pragma unroll
        for (int fi = 0; fi < 2; ++fi)
            #pragma unroll
            for (int fj = 0; fj < 2; ++fj) {
                a0[fi][fj] = __builtin_amdgcn_mfma_f32_16x16x32_bf16(fa[0][fi], fb[0][fj], a0[fi][fj], 0, 0, 0);
                a1[fi][fj] = __builtin_amdgcn_mfma_f32_16x16x32_bf16(fa[1][fi], fb[1][fj], a1[fi][fj], 0, 0, 0);
                a2[fi][fj] = __builtin_amdgcn_mfma_f32_16x16x32_bf16(fa[2][fi], fb[2][fj], a2[fi][fj], 0, 0, 0);
            }
    }

    // epilogue: C layout col=lane&15, row=(lane>>4)*4+reg (m89-verified)
    const float* A = abc;
    const float* Bv = abc + BSH;
    const float* Cv = abc + 2 * BSH;
    float lsum = 0.f;
    #pragma unroll
    for (int fj = 0; fj < 2; ++fj) {
        int j = J0 + wc * 32 + fj * 16 + lam;
        float aj = A[j], abj = aj + Bv[j], acj = aj + Cv[j];
        #pragma unroll
        for (int fi = 0; fi < 2; ++fi)
            #pragma unroll
            for (int r = 0; r < 4; ++r) {
                float s = fmaf(aj, a0[fi][fj][r], 1.0f)
                          - abj * a1[fi][fj][r] - acj * a2[fi][fj][r];
                lsum += fmaxf(s, 0.f);
            }
    }
    if (bj != bi) {
        #pragma unroll
        for (int fi = 0; fi < 2; ++fi)
            #pragma unroll
            for (int r = 0; r < 4; ++r) {
                int i = I0 + wr * 32 + fi * 16 + lag * 4 + r;
                float ai = A[i], abi = ai + Bv[i], aci = ai + Cv[i];
                #pragma unroll
                for (int fj = 0; fj < 2; ++fj) {
                    float s = fmaf(ai, a0[fi][fj][r], 1.0f)
                              - abi * a1[fi][fj][r] - aci * a2[fi][fj][r];
                    lsum += fmaxf(s, 0.f);
                }
            }
    }
    #pragma unroll
    for (int off = 32; off; off >>= 1) lsum += __shfl_down(lsum, off);
    if (lane == 0) sRed[wv] = lsum;
    __syncthreads();
    if (t == 0)
        pm[flat] = (double)(sRed[0] + sRed[1] + sRed[2] + sRed[3]);
}

// single-block tree reduce of all partials -> final loss scalar
__global__ __launch_bounds__(256) void k_reduce(const double* __restrict__ pp,
                                                const double* __restrict__ pm,
                                                float* __restrict__ out) {
    int t = threadIdx.x;
    double h2 = 0, r2 = 0, t2 = 0, wr = 0, mg = 0;
    for (int i = t; i < BSH; i += 256) {
        h2 += pp[(size_t)i * 4 + 0];
        r2 += pp[(size_t)i * 4 + 1];
        t2 += pp[(size_t)i * 4 + 2];
        wr += pp[(size_t)i * 4 + 3];
        mg += pm[i];
    }
    #pragma unroll
    for (int off = 32; off; off >>= 1) {
        h2 += __shfl_down(h2, off);
        r2 += __shfl_down(r2, off);
        t2 += __shfl_down(t2, off);
        wr += __shfl_down(wr, off);
        mg += __shfl_down(mg, off);
    }
    __shared__ double sred[5][4];
    int lane = t & 63, wv = t >> 6;
    if (lane == 0) {
        sred[0][wv] = h2; sred[1][wv] = r2; sred[2][wv] = t2;
        sred[3][wv] = wr; sred[4][wv] = mg;
    }
    __syncthreads();
    if (t == 0) {
        double H = sred[0][0] + sred[0][1] + sred[0][2] + sred[0][3];
        double R = sred[1][0] + sred[1][1] + sred[1][2] + sred[1][3];
        double T = sred[2][0] + sred[2][1] + sred[2][2] + sred[2][3];
        double W = sred[3][0] + sred[3][1] + sred[3][2] + sred[3][3];
        double M = sred[4][0] + sred[4][1] + sred[4][2] + sred[4][3];
        out[0] = (float)(M / (double)BSH + sqrt(W) * 0.01
                         + (sqrt(H) + sqrt(R) + sqrt(T)) * 0.01);
    }
}

// one block per relation: write Wr_new row (runs LAST: d_out scratch dead)
__global__ __launch_bounds__(256) void k_wrout(const float* __restrict__ Wr,
                                               const float* __restrict__ e,
                                               const int* __restrict__ winner,
                                               float* __restrict__ outWr) {
    int rel = blockIdx.x;
    int t = threadIdx.x;
    float* out = outWr + (size_t)rel * HID * HID;
    int j = winner[rel];
    if (j < 0) {
        const float* src = Wr + (size_t)rel * HID * HID;
        #pragma unroll 8
        for (int it = 0; it < 64; ++it) out[it * 256 + t] = src[it * 256 + t];
    } else {
        __shared__ float sep[HID], sen[HID];
        if (t < 128) sep[t] = e[(size_t)j * HID + t];
        else sen[t - 128] = e[(size_t)(j + BSH) * HID + (t - 128)];
        __syncthreads();
        #pragma unroll 8
        for (int it = 0; it < 64; ++it) {
            int ix = it * 256 + t;
            int hh = ix >> 7, kk = ix & 127;
            out[ix] = sen[hh] * sen[kk] - sep[hh] * sep[kk];
        }
    }
}

extern "C" void kernel_launch(void* const* d_in, const int* in_sizes, int n_in,
                              void* d_out, int out_size, void* d_ws, size_t ws_size,
                              hipStream_t stream) {
    const int* idx = (const int*)d_in[0];
    const float* ent = (const float*)d_in[1];
    const float* rel = (const float*)d_in[2];
    const float* Wr = (const float*)d_in[3];
    float* out = (float*)d_out;

    char* ws = (char*)d_ws;
    int* winner = (int*)(ws + 64);
    float* abc = (float*)(ws + 4096);
    float* e = (float*)(ws + 53248);
    // scratch in d_out (65.5 MB); consumed before k_wrout overwrites
    u32* S = (u32*)(out + 4);
    double* pp = (double*)((char*)d_out + 6291488);
    double* pm = (double*)((char*)d_out + 6422560);

    k_init<<<4, 256, 0, stream>>>(winner);
    k_prep<<<BSH, 256, 0, stream>>>(idx, ent, rel, e, S, abc, winner, pp);
    k_scoremm<<<dim3(64, 64), 256, 0, stream>>>((const unsigned short*)S, abc, pm);
    k_reduce<<<1, 256, 0, stream>>>(pp, pm, out);
    k_wrout<<<RELS, 256, 0, stream>>>(Wr, e, winner, out + 1);
}

// Round 6
// 212.265 us; speedup vs baseline: 2.3096x; 1.0486x over previous
//
#include <hip/hip_runtime.h>
#include <hip/hip_bf16.h>
#include <math.h>

#define HID 128
#define BSEQ 8192
#define BSH 4096
#define RELS 1000
#define KEXT 256   // 128 elems x (hi,lo) bf16 interleaved
#define NTILE 64   // 64x64 output tiles
#define NTRI 2080  // 65*64/2 triangle tiles

typedef unsigned int u32;
typedef unsigned short u16;
typedef __attribute__((ext_vector_type(8))) short bf16x8;
typedef __attribute__((ext_vector_type(4))) float f32x4;

// d_ws layout (bytes)  [proven available: 4.25 MB]:
//  [64, 64+4000)         int winner[1000]
//  [4096, 53248)         float abc[3*4096]: a | b | c
//  [53248, 4247552)      float e[8192][128]
// d_out scratch (consumed by k_reduce BEFORE k_wrout overwrites):
//  byte 16:       ushort S[3][4096][256]   (u | ep | en, [hi,lo] pairs)  6.29 MB
//  byte 6291488:  double part_prep[4096][4]  (h2, r2, t2, wrsq)          128 KB
//  byte 6422560:  double part_margin[2080]                               16.6 KB

__device__ inline u16 f2bf(float x) {  // RNE bf16
    u32 u = __float_as_uint(x);
    u32 r = (u + 0x7fff + ((u >> 16) & 1)) >> 16;
    return (u16)r;
}

__device__ inline u32 pack2bf(float x) {  // [hi, lo] packed u32
    u16 hi = f2bf(x);
    float hf = __uint_as_float((u32)hi << 16);
    u16 lo = f2bf(x - hf);
    return (u32)hi | ((u32)lo << 16);
}

#define GLOAD_LDS16(g, l) __builtin_amdgcn_global_load_lds( \
    (const __attribute__((address_space(1))) u32*)(g), \
    (__attribute__((address_space(3))) u32*)(l), 16, 0, 0)

__global__ void k_init(int* __restrict__ winner) {
    int t = blockIdx.x * blockDim.x + threadIdx.x;
    if (t < RELS) winner[t] = -1;
}

// Fused gather + norms + bf16-split + rowstats. Block b owns rows b (ep) and
// b+BSH (en). NO contended atomics: partials -> part_prep[b].
__global__ __launch_bounds__(256) void k_prep(const int* __restrict__ idx,
                                              const float* __restrict__ ent,
                                              const float* __restrict__ rel,
                                              float* __restrict__ e,
                                              u32* __restrict__ S,
                                              float* __restrict__ abc,
                                              int* __restrict__ winner,
                                              double* __restrict__ part) {
    const int b = blockIdx.x;
    const int half = threadIdx.x >> 7;   // 0=ep row b, 1=en row b+BSH
    const int k = threadIdx.x & 127;
    const int row = half ? (b + BSH) : b;
    const int i0 = idx[row * 3 + 0];
    const int i1 = idx[row * 3 + 1];
    const int i2 = idx[row * 3 + 2];
    const float h = ent[(size_t)i0 * HID + k];
    const float r = rel[(size_t)i1 * HID + k];
    const float t = ent[(size_t)i2 * HID + k];
    const float val = fabsf(h + r - t);
    e[(size_t)row * HID + k] = val;

    __shared__ float sE[2][128];
    __shared__ float sh[3][4];
    __shared__ float sPart[3][2];
    sE[half][k] = val;

    // norm partial sums (per wave)
    float hh = h * h, rr = r * r, tt = t * t;
    #pragma unroll
    for (int off = 32; off; off >>= 1) {
        hh += __shfl_down(hh, off);
        rr += __shfl_down(rr, off);
        tt += __shfl_down(tt, off);
    }
    int lane = threadIdx.x & 63, wv = threadIdx.x >> 6;
    if (lane == 0) { sh[0][wv] = hh; sh[1][wv] = rr; sh[2][wv] = tt; }
    __syncthreads();

    const float p = sE[0][k], n = sE[1][k];
    // bf16 splits: S row = 128 packed u32 ([hi,lo] per element; K-permutation ok)
    {
        size_t base = ((size_t)(1 + half) * BSH + b) * (KEXT / 2);
        S[base + k] = pack2bf(val);
        if (half == 0) {
            size_t ub = (size_t)b * (KEXT / 2);
            S[ub + k] = pack2bf(p + n);
        }
    }
    // rowstats on threads 0..127 (waves 0,1)
    if (half == 0) {
        float ak = p * n, bk = p * p, ck = n * n;
        #pragma unroll
        for (int off = 32; off; off >>= 1) {
            ak += __shfl_down(ak, off);
            bk += __shfl_down(bk, off);
            ck += __shfl_down(ck, off);
        }
        if (lane == 0) { sPart[0][wv] = ak; sPart[1][wv] = bk; sPart[2][wv] = ck; }
    }
    __syncthreads();
    if (threadIdx.x == 0) {
        float a = sPart[0][0] + sPart[0][1];
        float bb = sPart[1][0] + sPart[1][1];
        float c = sPart[2][0] + sPart[2][1];
        abc[b] = a; abc[BSH + b] = bb; abc[2 * BSH + b] = c;
        double ad = a, bd = bb, cd = c;
        part[(size_t)b * 4 + 0] = (double)(sh[0][0] + sh[0][1] + sh[0][2] + sh[0][3]);
        part[(size_t)b * 4 + 1] = (double)(sh[1][0] + sh[1][1] + sh[1][2] + sh[1][3]);
        part[(size_t)b * 4 + 2] = (double)(sh[2][0] + sh[2][1] + sh[2][2] + sh[2][3]);
        part[(size_t)b * 4 + 3] = cd * cd - 2.0 * ad * ad + bd * bd;
        atomicMax(&winner[i1], b);  // ~4 ops per address: uncontended
    }
}

// stage one BK=32 K-chunk of all 6 panels into LDS buffer (6 gload_lds / wave)
__device__ __forceinline__ void stage_chunk(const u16* __restrict__ S,
                                            int I0, int J0, int wv, int lane,
                                            int kc, u16* lds) {
    #pragma unroll
    for (int qq = 0; qq < 6; ++qq) {
        int q = wv * 6 + qq;
        int b = q * 1024 + lane * 16;      // byte cursor over 24KB
        int arr = b >> 12;                 // 0..5  (m*2+side)
        int within = b & 4095;
        int row = within >> 6;
        int colB = within & 63;
        int m = arr >> 1;
        int R0 = (arr & 1) ? J0 : I0;
        const u16* src = S + ((size_t)(m * BSH + R0 + row) << 8)
                           + kc * 32 + (colB >> 1);
        GLOAD_LDS16(src, &lds[q * 512]);
    }
}

// MFMA Gram kernel, v2: flat triangular grid (2080 blocks), double-buffered
// LDS, counted vmcnt(6) + raw s_barrier 2-phase pipeline (T3/T4-lite).
// Three K=256 bf16 NT-GEMMs (q=u.u, p2=ep.ep, p3=en.en).
// score(i,j) = a_j*q + 1 - (a_j+b_j)*p2 - (a_j+c_j)*p3
__global__ __launch_bounds__(256) void k_scoremm(const u16* __restrict__ S,
                                                 const float* __restrict__ abc,
                                                 double* __restrict__ pm) {
    // flat -> (bi, bj) with bi <= bj; off(bi) = bi*64 - bi*(bi-1)/2
    const int f = blockIdx.x;
    int bi = (int)(64.5f - sqrtf(64.5f * 64.5f - 2.0f * (float)f));
    while ((bi + 1) * NTILE - ((bi + 1) * bi) / 2 <= f) ++bi;
    while (bi * NTILE - (bi * (bi - 1)) / 2 > f) --bi;
    const int bj = bi + (f - (bi * NTILE - (bi * (bi - 1)) / 2));
    const int I0 = bi * 64, J0 = bj * 64;

    __shared__ __align__(16) u16 sAll[2][6 * 64 * 32];  // 2 x 24KB
    __shared__ float sRed[4];
    const int t = threadIdx.x;
    const int lane = t & 63, wv = t >> 6;
    const int wr = wv >> 1, wc = wv & 1;       // wave quadrant of 64x64
    const int lam = lane & 15, lag = lane >> 4;

    f32x4 a0[2][2] = {}, a1[2][2] = {}, a2[2][2] = {};  // q, p2, p3 accums

    // prologue: 2 chunks in flight (12 loads/wave)
    stage_chunk(S, I0, J0, wv, lane, 0, sAll[0]);
    stage_chunk(S, I0, J0, wv, lane, 1, sAll[1]);

    // one K-step: wait own stage-kc loads (counted), barrier (all waves' writes
    // visible), ds_read frags, lgkmcnt drain, barrier (all reads done), THEN
    // overwrite this buffer with stage kc+2, then MFMA.
#define KSTEP(KC, NWAIT)                                                      \
    {                                                                         \
        asm volatile("s_waitcnt vmcnt(" #NWAIT ")" ::: "memory");             \
        __builtin_amdgcn_sched_barrier(0);                                    \
        __builtin_amdgcn_s_barrier();                                         \
        __builtin_amdgcn_sched_barrier(0);                                    \
        const u16* buf = sAll[KC & 1];                                        \
        bf16x8 fa[3][2], fb[3][2];                                            \
        _Pragma("unroll")                                                     \
        for (int m = 0; m < 3; ++m) {                                         \
            _Pragma("unroll")                                                 \
            for (int ff = 0; ff < 2; ++ff) {                                  \
                fa[m][ff] = *(const bf16x8*)&buf[(m * 2 + 0) * 2048           \
                               + (wr * 32 + ff * 16 + lam) * 32 + lag * 8];   \
                fb[m][ff] = *(const bf16x8*)&buf[(m * 2 + 1) * 2048           \
                               + (wc * 32 + ff * 16 + lam) * 32 + lag * 8];   \
            }                                                                 \
        }                                                                     \
        asm volatile("s_waitcnt lgkmcnt(0)" ::: "memory");                    \
        __builtin_amdgcn_sched_barrier(0);                                    \
        __builtin_amdgcn_s_barrier();                                         \
        __builtin_amdgcn_sched_barrier(0);                                    \
        if ((KC) + 2 < 8)                                                     \
            stage_chunk(S, I0, J0, wv, lane, (KC) + 2, sAll[KC & 1]);         \
        _Pragma("unroll")                                                     \
        for (int fi = 0; fi < 2; ++fi) {                                      \
            _Pragma("unroll")                                                 \
            for (int fj = 0; fj < 2; ++fj) {                                  \
                a0[fi][fj] = __builtin_amdgcn_mfma_f32_16x16x32_bf16(         \
                    fa[0][fi], fb[0][fj], a0[fi][fj], 0, 0, 0);               \
                a1[fi][fj] = __builtin_amdgcn_mfma_f32_16x16x32_bf16(         \
                    fa[1][fi], fb[1][fj], a1[fi][fj], 0, 0, 0);               \
                a2[fi][fj] = __builtin_amdgcn_mfma_f32_16x16x32_bf16(         \
                    fa[2][fi], fb[2][fj], a2[fi][fj], 0, 0, 0);               \
            }                                                                 \
        }                                                                     \
    }

    KSTEP(0, 6) KSTEP(1, 6) KSTEP(2, 6) KSTEP(3, 6)
    KSTEP(4, 6) KSTEP(5, 6) KSTEP(6, 6) KSTEP(7, 0)
#undef KSTEP

    // epilogue: C layout col=lane&15, row=(lane>>4)*4+reg (m89-verified)
    const float* A = abc;
    const float* Bv = abc + BSH;
    const float* Cv = abc + 2 * BSH;
    float lsum = 0.f;
    #pragma unroll
    for (int fj = 0; fj < 2; ++fj) {
        int j = J0 + wc * 32 + fj * 16 + lam;
        float aj = A[j], abj = aj + Bv[j], acj = aj + Cv[j];
        #pragma unroll
        for (int fi = 0; fi < 2; ++fi)
            #pragma unroll
            for (int r = 0; r < 4; ++r) {
                float s = fmaf(aj, a0[fi][fj][r], 1.0f)
                          - abj * a1[fi][fj][r] - acj * a2[fi][fj][r];
                lsum += fmaxf(s, 0.f);
            }
    }
    if (bj != bi) {
        #pragma unroll
        for (int fi = 0; fi < 2; ++fi)
            #pragma unroll
            for (int r = 0; r < 4; ++r) {
                int i = I0 + wr * 32 + fi * 16 + lag * 4 + r;
                float ai = A[i], abi = ai + Bv[i], aci = ai + Cv[i];
                #pragma unroll
                for (int fj = 0; fj < 2; ++fj) {
                    float s = fmaf(ai, a0[fi][fj][r], 1.0f)
                              - abi * a1[fi][fj][r] - aci * a2[fi][fj][r];
                    lsum += fmaxf(s, 0.f);
                }
            }
    }
    #pragma unroll
    for (int off = 32; off; off >>= 1) lsum += __shfl_down(lsum, off);
    if (lane == 0) sRed[wv] = lsum;
    __syncthreads();
    if (t == 0)
        pm[f] = (double)(sRed[0] + sRed[1] + sRed[2] + sRed[3]);
}

// single-block tree reduce of all partials -> final loss scalar
__global__ __launch_bounds__(256) void k_reduce(const double* __restrict__ pp,
                                                const double* __restrict__ pm,
                                                float* __restrict__ out) {
    int t = threadIdx.x;
    double h2 = 0, r2 = 0, t2 = 0, wr = 0, mg = 0;
    for (int i = t; i < BSH; i += 256) {
        h2 += pp[(size_t)i * 4 + 0];
        r2 += pp[(size_t)i * 4 + 1];
        t2 += pp[(size_t)i * 4 + 2];
        wr += pp[(size_t)i * 4 + 3];
        if (i < NTRI) mg += pm[i];
    }
    #pragma unroll
    for (int off = 32; off; off >>= 1) {
        h2 += __shfl_down(h2, off);
        r2 += __shfl_down(r2, off);
        t2 += __shfl_down(t2, off);
        wr += __shfl_down(wr, off);
        mg += __shfl_down(mg, off);
    }
    __shared__ double sred[5][4];
    int lane = t & 63, wv = t >> 6;
    if (lane == 0) {
        sred[0][wv] = h2; sred[1][wv] = r2; sred[2][wv] = t2;
        sred[3][wv] = wr; sred[4][wv] = mg;
    }
    __syncthreads();
    if (t == 0) {
        double H = sred[0][0] + sred[0][1] + sred[0][2] + sred[0][3];
        double R = sred[1][0] + sred[1][1] + sred[1][2] + sred[1][3];
        double T = sred[2][0] + sred[2][1] + sred[2][2] + sred[2][3];
        double W = sred[3][0] + sred[3][1] + sred[3][2] + sred[3][3];
        double M = sred[4][0] + sred[4][1] + sred[4][2] + sred[4][3];
        out[0] = (float)(M / (double)BSH + sqrt(W) * 0.01
                         + (sqrt(H) + sqrt(R) + sqrt(T)) * 0.01);
    }
}

// one block per relation: write Wr_new row (runs LAST: d_out scratch dead)
__global__ __launch_bounds__(256) void k_wrout(const float* __restrict__ Wr,
                                               const float* __restrict__ e,
                                               const int* __restrict__ winner,
                                               float* __restrict__ outWr) {
    int rel = blockIdx.x;
    int t = threadIdx.x;
    float* out = outWr + (size_t)rel * HID * HID;
    int j = winner[rel];
    if (j < 0) {
        const float* src = Wr + (size_t)rel * HID * HID;
        #pragma unroll 8
        for (int it = 0; it < 64; ++it) out[it * 256 + t] = src[it * 256 + t];
    } else {
        __shared__ float sep[HID], sen[HID];
        if (t < 128) sep[t] = e[(size_t)j * HID + t];
        else sen[t - 128] = e[(size_t)(j + BSH) * HID + (t - 128)];
        __syncthreads();
        #pragma unroll 8
        for (int it = 0; it < 64; ++it) {
            int ix = it * 256 + t;
            int hh = ix >> 7, kk = ix & 127;
            out[ix] = sen[hh] * sen[kk] - sep[hh] * sep[kk];
        }
    }
}

extern "C" void kernel_launch(void* const* d_in, const int* in_sizes, int n_in,
                              void* d_out, int out_size, void* d_ws, size_t ws_size,
                              hipStream_t stream) {
    const int* idx = (const int*)d_in[0];
    const float* ent = (const float*)d_in[1];
    const float* rel = (const float*)d_in[2];
    const float* Wr = (const float*)d_in[3];
    float* out = (float*)d_out;

    char* ws = (char*)d_ws;
    int* winner = (int*)(ws + 64);
    float* abc = (float*)(ws + 4096);
    float* e = (float*)(ws + 53248);
    // scratch in d_out (65.5 MB); consumed before k_wrout overwrites
    u32* S = (u32*)(out + 4);
    double* pp = (double*)((char*)d_out + 6291488);
    double* pm = (double*)((char*)d_out + 6422560);

    k_init<<<4, 256, 0, stream>>>(winner);
    k_prep<<<BSH, 256, 0, stream>>>(idx, ent, rel, e, S, abc, winner, pp);
    k_scoremm<<<NTRI, 256, 0, stream>>>((const u16*)S, abc, pm);
    k_reduce<<<1, 256, 0, stream>>>(pp, pm, out);
    k_wrout<<<RELS, 256, 0, stream>>>(Wr, e, winner, out + 1);
}

// Round 7
// 211.381 us; speedup vs baseline: 2.3192x; 1.0042x over previous
//
#include <hip/hip_runtime.h>
#include <hip/hip_bf16.h>
#include <math.h>

#define HID 128
#define BSEQ 8192
#define BSH 4096
#define RELS 1000
#define KEXT 256   // 128 elems x (hi,lo) bf16 interleaved
#define NTILE 64   // 64x64 output tiles
#define NTRI 2080  // 65*64/2 triangle tiles

typedef unsigned int u32;
typedef unsigned short u16;
typedef __attribute__((ext_vector_type(8))) short bf16x8;
typedef __attribute__((ext_vector_type(4))) float f32x4;

// d_ws layout (bytes)  [proven available: 4.25 MB]:
//  [64, 64+4000)         int winner[1000]
//  [4096, 53248)         float abc[3*4096]: a | b | c
//  [53248, 4247552)      float e[8192][128]
// d_out scratch (consumed by k_reduce BEFORE k_wrout overwrites):
//  byte 16:       ushort S[3][4096][256]   (u | ep | en, [hi,lo] pairs)  6.29 MB
//  byte 6291488:  double part_prep[4096][4]  (h2, r2, t2, wrsq)          128 KB
//  byte 6422560:  double part_margin[2080]                               16.6 KB

__device__ inline u16 f2bf(float x) {  // RNE bf16
    u32 u = __float_as_uint(x);
    u32 r = (u + 0x7fff + ((u >> 16) & 1)) >> 16;
    return (u16)r;
}

__device__ inline u32 pack2bf(float x) {  // [hi, lo] packed u32
    u16 hi = f2bf(x);
    float hf = __uint_as_float((u32)hi << 16);
    u16 lo = f2bf(x - hf);
    return (u32)hi | ((u32)lo << 16);
}

#define GLOAD_LDS16(g, l) __builtin_amdgcn_global_load_lds( \
    (const __attribute__((address_space(1))) u32*)(g), \
    (__attribute__((address_space(3))) u32*)(l), 16, 0, 0)

__global__ void k_init(int* __restrict__ winner) {
    int t = blockIdx.x * blockDim.x + threadIdx.x;
    if (t < RELS) winner[t] = -1;
}

// Fused gather + norms + bf16-split + rowstats. Block b owns rows b (ep) and
// b+BSH (en). NO contended atomics: partials -> part_prep[b].
__global__ __launch_bounds__(256) void k_prep(const int* __restrict__ idx,
                                              const float* __restrict__ ent,
                                              const float* __restrict__ rel,
                                              float* __restrict__ e,
                                              u32* __restrict__ S,
                                              float* __restrict__ abc,
                                              int* __restrict__ winner,
                                              double* __restrict__ part) {
    const int b = blockIdx.x;
    const int half = threadIdx.x >> 7;   // 0=ep row b, 1=en row b+BSH
    const int k = threadIdx.x & 127;
    const int row = half ? (b + BSH) : b;
    const int i0 = idx[row * 3 + 0];
    const int i1 = idx[row * 3 + 1];
    const int i2 = idx[row * 3 + 2];
    const float h = ent[(size_t)i0 * HID + k];
    const float r = rel[(size_t)i1 * HID + k];
    const float t = ent[(size_t)i2 * HID + k];
    const float val = fabsf(h + r - t);
    e[(size_t)row * HID + k] = val;

    __shared__ float sE[2][128];
    __shared__ float sh[3][4];
    __shared__ float sPart[3][2];
    sE[half][k] = val;

    // norm partial sums (per wave)
    float hh = h * h, rr = r * r, tt = t * t;
    #pragma unroll
    for (int off = 32; off; off >>= 1) {
        hh += __shfl_down(hh, off);
        rr += __shfl_down(rr, off);
        tt += __shfl_down(tt, off);
    }
    int lane = threadIdx.x & 63, wv = threadIdx.x >> 6;
    if (lane == 0) { sh[0][wv] = hh; sh[1][wv] = rr; sh[2][wv] = tt; }
    __syncthreads();

    const float p = sE[0][k], n = sE[1][k];
    // bf16 splits: S row = 128 packed u32 ([hi,lo] per element; K-permutation ok)
    {
        size_t base = ((size_t)(1 + half) * BSH + b) * (KEXT / 2);
        S[base + k] = pack2bf(val);
        if (half == 0) {
            size_t ub = (size_t)b * (KEXT / 2);
            S[ub + k] = pack2bf(p + n);
        }
    }
    // rowstats on threads 0..127 (waves 0,1)
    if (half == 0) {
        float ak = p * n, bk = p * p, ck = n * n;
        #pragma unroll
        for (int off = 32; off; off >>= 1) {
            ak += __shfl_down(ak, off);
            bk += __shfl_down(bk, off);
            ck += __shfl_down(ck, off);
        }
        if (lane == 0) { sPart[0][wv] = ak; sPart[1][wv] = bk; sPart[2][wv] = ck; }
    }
    __syncthreads();
    if (threadIdx.x == 0) {
        float a = sPart[0][0] + sPart[0][1];
        float bb = sPart[1][0] + sPart[1][1];
        float c = sPart[2][0] + sPart[2][1];
        abc[b] = a; abc[BSH + b] = bb; abc[2 * BSH + b] = c;
        double ad = a, bd = bb, cd = c;
        part[(size_t)b * 4 + 0] = (double)(sh[0][0] + sh[0][1] + sh[0][2] + sh[0][3]);
        part[(size_t)b * 4 + 1] = (double)(sh[1][0] + sh[1][1] + sh[1][2] + sh[1][3]);
        part[(size_t)b * 4 + 2] = (double)(sh[2][0] + sh[2][1] + sh[2][2] + sh[2][3]);
        part[(size_t)b * 4 + 3] = cd * cd - 2.0 * ad * ad + bd * bd;
        atomicMax(&winner[i1], b);  // ~4 ops per address: uncontended
    }
}

// stage one BK=32 K-chunk of all 6 panels into LDS buffer (6 gload_lds / wave).
// LDS dest is linear (gload_lds constraint); SOURCE block is XOR-swizzled:
// LDS(row, bl) holds global block bl ^ ((row>>1)&3)  [T2 bank-conflict fix].
__device__ __forceinline__ void stage_chunk(const u16* __restrict__ S,
                                            int I0, int J0, int wv, int lane,
                                            int kc, u16* lds) {
    #pragma unroll
    for (int qq = 0; qq < 6; ++qq) {
        int q = wv * 6 + qq;
        int b = q * 1024 + lane * 16;      // byte cursor over 24KB
        int arr = b >> 12;                 // 0..5  (m*2+side)
        int within = b & 4095;
        int row = within >> 6;
        int colB = within & 63;
        int m = arr >> 1;
        int R0 = (arr & 1) ? J0 : I0;
        int sbl = (colB >> 4) ^ ((row >> 1) & 3);   // swizzled 16B-block idx
        const u16* src = S + ((size_t)(m * BSH + R0 + row) << 8)
                           + kc * 32 + (sbl << 3);
        GLOAD_LDS16(src, &lds[q * 512]);
    }
}

// MFMA Gram kernel, v3: flat triangular grid, double-buffered LDS, counted
// vmcnt(6) 2-phase pipeline, XOR-swizzled LDS (conflict-free ds_read_b128).
// Three K=256 bf16 NT-GEMMs (q=u.u, p2=ep.ep, p3=en.en).
// score(i,j) = a_j*q + 1 - (a_j+b_j)*p2 - (a_j+c_j)*p3
__global__ __launch_bounds__(256) void k_scoremm(const u16* __restrict__ S,
                                                 const float* __restrict__ abc,
                                                 double* __restrict__ pm) {
    // flat -> (bi, bj) with bi <= bj; off(bi) = bi*64 - bi*(bi-1)/2
    const int f = blockIdx.x;
    int bi = (int)(64.5f - sqrtf(64.5f * 64.5f - 2.0f * (float)f));
    while ((bi + 1) * NTILE - ((bi + 1) * bi) / 2 <= f) ++bi;
    while (bi * NTILE - (bi * (bi - 1)) / 2 > f) --bi;
    const int bj = bi + (f - (bi * NTILE - (bi * (bi - 1)) / 2));
    const int I0 = bi * 64, J0 = bj * 64;

    __shared__ __align__(16) u16 sAll[2][6 * 64 * 32];  // 2 x 24KB
    __shared__ float sRed[4];
    const int t = threadIdx.x;
    const int lane = t & 63, wv = t >> 6;
    const int wr = wv >> 1, wc = wv & 1;       // wave quadrant of 64x64
    const int lam = lane & 15, lag = lane >> 4;
    const int swz = (lam >> 1) & 3;            // row-bits 1..2 (I==J frag rows)
    const int fofs = ((lag ^ swz) << 3);       // swizzled frag elem offset

    f32x4 a0[2][2] = {}, a1[2][2] = {}, a2[2][2] = {};  // q, p2, p3 accums

    // prologue: 2 chunks in flight (12 loads/wave)
    stage_chunk(S, I0, J0, wv, lane, 0, sAll[0]);
    stage_chunk(S, I0, J0, wv, lane, 1, sAll[1]);

    // one K-step: wait own stage-kc loads (counted), barrier (all waves' writes
    // visible), ds_read frags, lgkmcnt drain, barrier (all reads done), THEN
    // overwrite this buffer with stage kc+2, then MFMA.
#define KSTEP(KC, NWAIT)                                                      \
    {                                                                         \
        asm volatile("s_waitcnt vmcnt(" #NWAIT ")" ::: "memory");             \
        __builtin_amdgcn_sched_barrier(0);                                    \
        __builtin_amdgcn_s_barrier();                                         \
        __builtin_amdgcn_sched_barrier(0);                                    \
        const u16* buf = sAll[KC & 1];                                        \
        bf16x8 fa[3][2], fb[3][2];                                            \
        _Pragma("unroll")                                                     \
        for (int m = 0; m < 3; ++m) {                                         \
            _Pragma("unroll")                                                 \
            for (int ff = 0; ff < 2; ++ff) {                                  \
                fa[m][ff] = *(const bf16x8*)&buf[(m * 2 + 0) * 2048           \
                               + (wr * 32 + ff * 16 + lam) * 32 + fofs];      \
                fb[m][ff] = *(const bf16x8*)&buf[(m * 2 + 1) * 2048           \
                               + (wc * 32 + ff * 16 + lam) * 32 + fofs];      \
            }                                                                 \
        }                                                                     \
        asm volatile("s_waitcnt lgkmcnt(0)" ::: "memory");                    \
        __builtin_amdgcn_sched_barrier(0);                                    \
        __builtin_amdgcn_s_barrier();                                         \
        __builtin_amdgcn_sched_barrier(0);                                    \
        if ((KC) + 2 < 8)                                                     \
            stage_chunk(S, I0, J0, wv, lane, (KC) + 2, sAll[KC & 1]);         \
        _Pragma("unroll")                                                     \
        for (int fi = 0; fi < 2; ++fi) {                                      \
            _Pragma("unroll")                                                 \
            for (int fj = 0; fj < 2; ++fj) {                                  \
                a0[fi][fj] = __builtin_amdgcn_mfma_f32_16x16x32_bf16(         \
                    fa[0][fi], fb[0][fj], a0[fi][fj], 0, 0, 0);               \
                a1[fi][fj] = __builtin_amdgcn_mfma_f32_16x16x32_bf16(         \
                    fa[1][fi], fb[1][fj], a1[fi][fj], 0, 0, 0);               \
                a2[fi][fj] = __builtin_amdgcn_mfma_f32_16x16x32_bf16(         \
                    fa[2][fi], fb[2][fj], a2[fi][fj], 0, 0, 0);               \
            }                                                                 \
        }                                                                     \
    }

    KSTEP(0, 6) KSTEP(1, 6) KSTEP(2, 6) KSTEP(3, 6)
    KSTEP(4, 6) KSTEP(5, 6) KSTEP(6, 6) KSTEP(7, 0)
#undef KSTEP

    // epilogue: C layout col=lane&15, row=(lane>>4)*4+reg (m89-verified)
    const float* A = abc;
    const float* Bv = abc + BSH;
    const float* Cv = abc + 2 * BSH;
    float lsum = 0.f;
    #pragma unroll
    for (int fj = 0; fj < 2; ++fj) {
        int j = J0 + wc * 32 + fj * 16 + lam;
        float aj = A[j], abj = aj + Bv[j], acj = aj + Cv[j];
        #pragma unroll
        for (int fi = 0; fi < 2; ++fi)
            #pragma unroll
            for (int r = 0; r < 4; ++r) {
                float s = fmaf(aj, a0[fi][fj][r], 1.0f)
                          - abj * a1[fi][fj][r] - acj * a2[fi][fj][r];
                lsum += fmaxf(s, 0.f);
            }
    }
    if (bj != bi) {
        #pragma unroll
        for (int fi = 0; fi < 2; ++fi)
            #pragma unroll
            for (int r = 0; r < 4; ++r) {
                int i = I0 + wr * 32 + fi * 16 + lag * 4 + r;
                float ai = A[i], abi = ai + Bv[i], aci = ai + Cv[i];
                #pragma unroll
                for (int fj = 0; fj < 2; ++fj) {
                    float s = fmaf(ai, a0[fi][fj][r], 1.0f)
                              - abi * a1[fi][fj][r] - aci * a2[fi][fj][r];
                    lsum += fmaxf(s, 0.f);
                }
            }
    }
    #pragma unroll
    for (int off = 32; off; off >>= 1) lsum += __shfl_down(lsum, off);
    if (lane == 0) sRed[wv] = lsum;
    __syncthreads();
    if (t == 0)
        pm[f] = (double)(sRed[0] + sRed[1] + sRed[2] + sRed[3]);
}

// single-block tree reduce of all partials -> final loss scalar
__global__ __launch_bounds__(256) void k_reduce(const double* __restrict__ pp,
                                                const double* __restrict__ pm,
                                                float* __restrict__ out) {
    int t = threadIdx.x;
    double h2 = 0, r2 = 0, t2 = 0, wr = 0, mg = 0;
    for (int i = t; i < BSH; i += 256) {
        h2 += pp[(size_t)i * 4 + 0];
        r2 += pp[(size_t)i * 4 + 1];
        t2 += pp[(size_t)i * 4 + 2];
        wr += pp[(size_t)i * 4 + 3];
        if (i < NTRI) mg += pm[i];
    }
    #pragma unroll
    for (int off = 32; off; off >>= 1) {
        h2 += __shfl_down(h2, off);
        r2 += __shfl_down(r2, off);
        t2 += __shfl_down(t2, off);
        wr += __shfl_down(wr, off);
        mg += __shfl_down(mg, off);
    }
    __shared__ double sred[5][4];
    int lane = t & 63, wv = t >> 6;
    if (lane == 0) {
        sred[0][wv] = h2; sred[1][wv] = r2; sred[2][wv] = t2;
        sred[3][wv] = wr; sred[4][wv] = mg;
    }
    __syncthreads();
    if (t == 0) {
        double H = sred[0][0] + sred[0][1] + sred[0][2] + sred[0][3];
        double R = sred[1][0] + sred[1][1] + sred[1][2] + sred[1][3];
        double T = sred[2][0] + sred[2][1] + sred[2][2] + sred[2][3];
        double W = sred[3][0] + sred[3][1] + sred[3][2] + sred[3][3];
        double M = sred[4][0] + sred[4][1] + sred[4][2] + sred[4][3];
        out[0] = (float)(M / (double)BSH + sqrt(W) * 0.01
                         + (sqrt(H) + sqrt(R) + sqrt(T)) * 0.01);
    }
}

// one block per relation: write Wr_new row (runs LAST: d_out scratch dead)
__global__ __launch_bounds__(256) void k_wrout(const float* __restrict__ Wr,
                                               const float* __restrict__ e,
                                               const int* __restrict__ winner,
                                               float* __restrict__ outWr) {
    int rel = blockIdx.x;
    int t = threadIdx.x;
    float* out = outWr + (size_t)rel * HID * HID;
    int j = winner[rel];
    if (j < 0) {
        const float* src = Wr + (size_t)rel * HID * HID;
        #pragma unroll 8
        for (int it = 0; it < 64; ++it) out[it * 256 + t] = src[it * 256 + t];
    } else {
        __shared__ float sep[HID], sen[HID];
        if (t < 128) sep[t] = e[(size_t)j * HID + t];
        else sen[t - 128] = e[(size_t)(j + BSH) * HID + (t - 128)];
        __syncthreads();
        #pragma unroll 8
        for (int it = 0; it < 64; ++it) {
            int ix = it * 256 + t;
            int hh = ix >> 7, kk = ix & 127;
            out[ix] = sen[hh] * sen[kk] - sep[hh] * sep[kk];
        }
    }
}

extern "C" void kernel_launch(void* const* d_in, const int* in_sizes, int n_in,
                              void* d_out, int out_size, void* d_ws, size_t ws_size,
                              hipStream_t stream) {
    const int* idx = (const int*)d_in[0];
    const float* ent = (const float*)d_in[1];
    const float* rel = (const float*)d_in[2];
    const float* Wr = (const float*)d_in[3];
    float* out = (float*)d_out;

    char* ws = (char*)d_ws;
    int* winner = (int*)(ws + 64);
    float* abc = (float*)(ws + 4096);
    float* e = (float*)(ws + 53248);
    // scratch in d_out (65.5 MB); consumed before k_wrout overwrites
    u32* S = (u32*)(out + 4);
    double* pp = (double*)((char*)d_out + 6291488);
    double* pm = (double*)((char*)d_out + 6422560);

    k_init<<<4, 256, 0, stream>>>(winner);
    k_prep<<<BSH, 256, 0, stream>>>(idx, ent, rel, e, S, abc, winner, pp);
    k_scoremm<<<NTRI, 256, 0, stream>>>((const u16*)S, abc, pm);
    k_reduce<<<1, 256, 0, stream>>>(pp, pm, out);
    k_wrout<<<RELS, 256, 0, stream>>>(Wr, e, winner, out + 1);
}